// Round 19
// baseline (518.769 us; speedup 1.0000x reference)
//
#include <hip/hip_runtime.h>
#include <cstdint>
#include <cstddef>

#define B_   2
#define S_   2048
#define D_   4096
#define H_   32
#define KVH_ 8
#define HD_  128

typedef unsigned short u16;
typedef short     bf16x8 __attribute__((ext_vector_type(8)));
typedef float     f32x4  __attribute__((ext_vector_type(4)));
typedef float     f32x16 __attribute__((ext_vector_type(16)));
typedef u16       u16x8  __attribute__((ext_vector_type(8)));
typedef uint32_t  u32x2  __attribute__((ext_vector_type(2)));
typedef uint32_t  u32x4  __attribute__((ext_vector_type(4)));

__device__ __forceinline__ u16 f2bf(float f) {
  union { float f; uint32_t u; } v; v.f = f;
  uint32_t u = v.u;
  return (u16)((u + 0x7fffu + ((u >> 16) & 1u)) >> 16);
}
__device__ __forceinline__ float bf2f(u16 h) {
  union { uint32_t u; float f; } v; v.u = ((uint32_t)h) << 16;
  return v.f;
}
__device__ __forceinline__ uint32_t cvtpk(float lo, float hi_) {
  uint32_t r; asm("v_cvt_pk_bf16_f32 %0, %1, %2" : "=v"(r) : "v"(lo), "v"(hi_)); return r;
}
__device__ __forceinline__ float exp2v(float x) {
  float r; asm("v_exp_f32 %0, %1" : "=v"(r) : "v"(x)); return r;
}

__device__ __forceinline__ void gl_lds16(const void* g, void* l) {
  __builtin_amdgcn_global_load_lds(
      (const __attribute__((address_space(1))) void*)g,
      (__attribute__((address_space(3))) void*)l, 16, 0, 0);
}

#define MFMA(a, b, c)  __builtin_amdgcn_mfma_f32_16x16x32_bf16((a), (b), (c), 0, 0, 0)
#define MFMA32(a, b, c) __builtin_amdgcn_mfma_f32_32x32x16_bf16((a), (b), (c), 0, 0, 0)
#define PLSWAP(x, y) asm volatile("v_permlane32_swap_b32 %0, %1" : "+v"(x), "+v"(y))

// ---------------- merged cast f32 -> bf16 (x, wq, wk, wv in one launch) -------
__global__ void cast4_kernel(const float* __restrict__ x, const float* __restrict__ wq,
                             const float* __restrict__ wk, const float* __restrict__ wv,
                             u16* __restrict__ xb, u16* __restrict__ wqb,
                             u16* __restrict__ wkb, u16* __restrict__ wvb) {
  int i = blockIdx.x * 256 + threadIdx.x;   // u16x8 group index, total 5242880
  const float* src; u16* dst; int off;
  if (i < 2097152)      { src = x;  dst = xb;  off = i; }
  else if (i < 4194304) { src = wq; dst = wqb; off = i - 2097152; }
  else if (i < 4718592) { src = wk; dst = wkb; off = i - 4194304; }
  else                  { src = wv; dst = wvb; off = i - 4718592; }
  const float4* p = (const float4*)src + (size_t)off * 2;
  float4 a = p[0], b = p[1];
  u16x8 r;
  r[0] = f2bf(a.x); r[1] = f2bf(a.y); r[2] = f2bf(a.z); r[3] = f2bf(a.w);
  r[4] = f2bf(b.x); r[5] = f2bf(b.y); r[6] = f2bf(b.z); r[7] = f2bf(b.w);
  *((u16x8*)dst + off) = r;
}

__global__ void cast_kernel(const float* __restrict__ in, u16* __restrict__ out, int n8) {
  int i = blockIdx.x * blockDim.x + threadIdx.x;
  if (i >= n8) return;
  const float4* p = (const float4*)in + (size_t)i * 2;
  float4 a = p[0], b = p[1];
  u16x8 r;
  r[0] = f2bf(a.x); r[1] = f2bf(a.y); r[2] = f2bf(a.z); r[3] = f2bf(a.w);
  r[4] = f2bf(b.x); r[5] = f2bf(b.y); r[6] = f2bf(b.z); r[7] = f2bf(b.w);
  *((u16x8*)out + i) = r;
}

// ---------------- GEMM-NT 128^2 (known-good; used for fused K/V proj) ---------
template <bool OUT_F32>
__global__ __launch_bounds__(256, 2)
void gemm_bt(const u16* __restrict__ A, const u16* __restrict__ Bw,
             void* __restrict__ C, int M, int N, int K) {
  __shared__ u16 lA[128 * 32];
  __shared__ u16 lB[128 * 32];
  const int tid = threadIdx.x;
  const int w = tid >> 6, l = tid & 63;
  const int lc = l & 15, lg = l >> 4;
  const int bn = blockIdx.x, bm = blockIdx.y;
  const int wr = w >> 1, wc = w & 1;
  const u16* Ab = A + (size_t)(bm * 128) * K;
  const u16* Bb = Bw + (size_t)(bn * 128) * K;
  const int srow = l >> 2;
  const int scol = (l & 3) * 8;

  f32x4 acc[4][4];
#pragma unroll
  for (int i = 0; i < 4; ++i)
#pragma unroll
    for (int j = 0; j < 4; ++j) acc[i][j] = (f32x4){0.f, 0.f, 0.f, 0.f};

  const int nk = K >> 5;
  for (int kt = 0; kt < nk; ++kt) {
    const int k0 = kt * 32;
    __syncthreads();
#pragma unroll
    for (int i = 0; i < 2; ++i) {
      const int rowA = (w * 2 + i) * 16;
      gl_lds16(Ab + (size_t)(rowA + srow) * K + k0 + scol, &lA[rowA * 32]);
      gl_lds16(Bb + (size_t)(rowA + srow) * K + k0 + scol, &lB[rowA * 32]);
    }
    __syncthreads();
    bf16x8 af[4], bfr[4];
#pragma unroll
    for (int mi = 0; mi < 4; ++mi)
      af[mi] = *(const bf16x8*)&lA[(wr * 64 + mi * 16 + lc) * 32 + lg * 8];
#pragma unroll
    for (int ni = 0; ni < 4; ++ni)
      bfr[ni] = *(const bf16x8*)&lB[(wc * 64 + ni * 16 + lc) * 32 + lg * 8];
#pragma unroll
    for (int mi = 0; mi < 4; ++mi)
#pragma unroll
      for (int ni = 0; ni < 4; ++ni)
        acc[mi][ni] = MFMA(af[mi], bfr[ni], acc[mi][ni]);
  }

#pragma unroll
  for (int mi = 0; mi < 4; ++mi)
#pragma unroll
    for (int ni = 0; ni < 4; ++ni)
#pragma unroll
      for (int r = 0; r < 4; ++r) {
        const int row = bm * 128 + wr * 64 + mi * 16 + lg * 4 + r;
        const int col = bn * 128 + wc * 64 + ni * 16 + lc;
        if constexpr (OUT_F32)
          ((float*)C)[(size_t)row * N + col] = acc[mi][ni][r];
        else
          ((u16*)C)[(size_t)row * N + col] = f2bf(acc[mi][ni][r]);
      }
}

// ---------------- GEMM-NT 256^2, BK=64, Gray-code, SINGLE vmcnt/tile ----------
// r15-proven SCHEDULE (barriers/vmcnt/staging byte-identical); MFMA shape
// switched 16x16x32 -> 32x32x16 (2495 vs 2075 TF measured; -17% matrix-pipe
// time; identical b128 read counts per phase). Operand layout per K=16 step:
// lane l holds [l&31][(l>>5)*8+j] (attn-verified). C/D: col=l&31,
// row=(r&3)+8*(r>>2)+4*(l>>5) (m74/m101-verified).
// MODE: 0 bf16 C, 1 f32 C, 2 fused Q-RoPE -> [b][h][s][128].
template <int MODE>
__global__ __launch_bounds__(512, 2)
void gemm256_bt(const u16* __restrict__ A, const u16* __restrict__ Bw,
                void* __restrict__ C, int M, int N, int K,
                const float* __restrict__ fr, float qscale) {
  __shared__ u16 sA[2 * 256 * 64];
  __shared__ u16 sB[2 * 256 * 64];
  const int tid = threadIdx.x;
  const int w = tid >> 6, l = tid & 63;
  const int q32l = l & 31, hi32 = l >> 5;
  const int wm = w >> 2, wn = w & 3;          // 2 x 4 wave grid
  const int nbn = N >> 8;
  const int nwg = (M >> 8) * nbn;
  const int cpx = nwg >> 3;
  const int lin = blockIdx.x;
  const int swz = (lin & 7) * cpx + (lin >> 3);
  const int bm = swz / nbn, bn = swz % nbn;
  const u16* Ab = A + (size_t)(bm * 256) * K;
  const u16* Bb = Bw + (size_t)(bn * 256) * K;
  const int lr = l >> 3;
  const int scc = ((l & 7) ^ lr) * 8;
  int cx32[4];   // chunk for K=16 step s: (s*2 + hi32) ^ (row&7), row&7 == l&7
#pragma unroll
  for (int s = 0; s < 4; ++s) cx32[s] = ((s * 2 + hi32) ^ (l & 7)) * 8;

  f32x16 acc[2][2][2];  // [ha][hb][rt]
#pragma unroll
  for (int i = 0; i < 2; ++i)
#pragma unroll
    for (int j = 0; j < 2; ++j)
#pragma unroll
      for (int k2 = 0; k2 < 2; ++k2)
#pragma unroll
        for (int r = 0; r < 16; ++r) acc[i][j][k2][r] = 0.f;

  auto STAGEA = [&](int buf, int t1, int h) {
    const int k0 = t1 * 64;
#pragma unroll
    for (int j = 0; j < 2; ++j) {
      const int r0 = h * 128 + w * 16 + j * 8;
      gl_lds16(Ab + (size_t)(r0 + lr) * K + k0 + scc, &sA[buf * 16384 + r0 * 64]);
    }
  };
  auto STAGEB = [&](int buf, int t1, int h) {
    const int k0 = t1 * 64;
#pragma unroll
    for (int j = 0; j < 2; ++j) {
      const int r0 = h * 128 + w * 16 + j * 8;
      gl_lds16(Bb + (size_t)(r0 + lr) * K + k0 + scc, &sB[buf * 16384 + r0 * 64]);
    }
  };

  bf16x8 a0r[2][4], a1r[2][4], b0r[4], b1r[4];
  auto LDA0 = [&](int cb) {
#pragma unroll
    for (int rt = 0; rt < 2; ++rt)
#pragma unroll
      for (int s = 0; s < 4; ++s)
        a0r[rt][s] = *(const bf16x8*)
            &sA[cb + (wm * 64 + rt * 32 + q32l) * 64 + cx32[s]];
  };
  auto LDA1 = [&](int cb) {
#pragma unroll
    for (int rt = 0; rt < 2; ++rt)
#pragma unroll
      for (int s = 0; s < 4; ++s)
        a1r[rt][s] = *(const bf16x8*)
            &sA[cb + (128 + wm * 64 + rt * 32 + q32l) * 64 + cx32[s]];
  };
  auto LDB0 = [&](int cb) {
#pragma unroll
    for (int s = 0; s < 4; ++s)
      b0r[s] = *(const bf16x8*)
          &sB[cb + (wn * 32 + q32l) * 64 + cx32[s]];
  };
  auto LDB1 = [&](int cb) {
#pragma unroll
    for (int s = 0; s < 4; ++s)
      b1r[s] = *(const bf16x8*)
          &sB[cb + (128 + wn * 32 + q32l) * 64 + cx32[s]];
  };

#define VMW(N_) asm volatile("s_waitcnt vmcnt(" #N_ ")" ::: "memory")
#define BARR do { __builtin_amdgcn_s_barrier(); asm volatile("" ::: "memory"); } while (0)
#define LGKM do { asm volatile("s_waitcnt lgkmcnt(0)" ::: "memory"); \
                  __builtin_amdgcn_sched_barrier(0); } while (0)
#define MMQ(AF, HA, HB, BF) do { __builtin_amdgcn_s_setprio(1); \
  _Pragma("unroll") for (int s = 0; s < 4; ++s) \
  _Pragma("unroll") for (int rt = 0; rt < 2; ++rt) \
    acc[HA][HB][rt] = MFMA32(AF[rt][s], BF[s], acc[HA][HB][rt]); \
  __builtin_amdgcn_s_setprio(0); } while (0)

  const int nk = K >> 6;
  // prologue: queue order [t0:A0, t0:B0, t0:B1, t0:A1, t1:A0, t1:B0] (12 loads)
  STAGEA(0, 0, 0); STAGEB(0, 0, 0);
  STAGEB(0, 0, 1); STAGEA(0, 0, 1);
  STAGEA(1, 1, 0); STAGEB(1, 1, 0);

  for (int t = 0; t < nk; ++t) {
    const int cur = t & 1;
    const int cb = cur * 16384;
    const int nb = cur ^ 1;
    const bool n1 = (t + 1 < nk), n2 = (t + 2 < nk);

    // ---- P0: quadrant (0,0); reads A0+B0. SINGLE wait drains all of tile t --
    if (n1) VMW(4); else VMW(0);
    BARR;
    LDA0(cb); LDB0(cb);
    if (n1) { STAGEB(nb, t + 1, 1); STAGEA(nb, t + 1, 1); }
    LGKM;
    MMQ(a0r, 0, 0, b0r);

    // ---- P1: quadrant (0,1); reads B1 (already landed; no wait) ----
    BARR;
    LDB1(cb);
    LGKM;
    MMQ(a0r, 0, 1, b1r);

    // ---- P2: quadrant (1,1); reads A1 (already landed; no wait) ----
    BARR;
    LDA1(cb);
    if (n2) STAGEA(cur, t + 2, 0);
    LGKM;
    MMQ(a1r, 1, 1, b1r);

    // ---- P3: quadrant (1,0); no reads ----
    if (n2) STAGEB(cur, t + 2, 0);
    MMQ(a1r, 1, 0, b0r);
  }
#undef VMW
#undef BARR
#undef LGKM
#undef MMQ

  // ---- epilogue: C/D col=l&31, row=(r&3)+8*(r>>2)+4*hi32 ----
#pragma unroll
  for (int ha = 0; ha < 2; ++ha)
#pragma unroll
    for (int hb = 0; hb < 2; ++hb)
#pragma unroll
      for (int rt = 0; rt < 2; ++rt)
#pragma unroll
        for (int r = 0; r < 16; ++r) {
          const int row = bm * 256 + ha * 128 + wm * 64 + rt * 32 +
                          (r & 3) + 8 * (r >> 2) + 4 * hi32;
          const int col = bn * 256 + hb * 128 + wn * 32 + q32l;
          const float v = acc[ha][hb][rt][r];
          if constexpr (MODE == 1) {
            ((float*)C)[(size_t)row * N + col] = v;
          } else if constexpr (MODE == 0) {
            ((u16*)C)[(size_t)row * N + col] = f2bf(v);
          } else {
            // fused RoPE: d parity = lane parity; xor-1 stays in 32-lane half
            const float pv = __shfl_xor(v, 1, 64);
            const int b = row >> 11, s = row & (S_ - 1);
            const int h = col >> 7, d = col & 127;
            const float2 cs = ((const float2*)fr)[s * 64 + (d >> 1)];
            const float o = ((l & 1) == 0) ? (v * cs.x - pv * cs.y)
                                           : (v * cs.x + pv * cs.y);
            ((u16*)C)[(((size_t)(b * H_ + h) * S_ + s)) * HD_ + d] =
                f2bf(o * qscale);
          }
        }
}

// ---------------- RoPE (row stride / col offset parametrized) ----------------
template <int NH, int STRIDE, int OFF>
__global__ void rope_kernel(const u16* __restrict__ lin, const float* __restrict__ fr,
                            u16* __restrict__ out, float scale) {
  int idx = blockIdx.x * 256 + threadIdx.x;
  const int total = B_ * S_ * NH * 64;
  if (idx >= total) return;
  const int i = idx & 63;
  const int h = (idx >> 6) % NH;
  const int t = idx / (64 * NH);
  const int s = t & (S_ - 1);
  const int b = t >> 11;
  const size_t src = (size_t)t * STRIDE + OFF + h * HD_ + 2 * i;
  const float x0 = bf2f(lin[src]);
  const float x1 = bf2f(lin[src + 1]);
  const float2 cs = ((const float2*)fr)[s * 64 + i];
  const float o0 = (x0 * cs.x - x1 * cs.y) * scale;
  const float o1 = (x1 * cs.x + x0 * cs.y) * scale;
  const size_t dst = ((size_t)((b * NH + h) * S_ + s)) * HD_ + 2 * i;
  out[dst] = f2bf(o0);
  out[dst + 1] = f2bf(o1);
}

// ---------------- V transpose (reads fused KV buffer, V at col offset 1024) ---
__global__ void vtrans_kernel(const u16* __restrict__ kvlin, u16* __restrict__ vt) {
  __shared__ u16 tile[32][33];
  const int tx = threadIdx.x, ty = threadIdx.y;  // (32, 8)
  const int s0 = blockIdx.x * 32;
  const int d0 = blockIdx.y * 32;
  const int bk = blockIdx.z;
  const int b = bk >> 3, kv = bk & 7;
#pragma unroll
  for (int r = 0; r < 4; ++r) {
    const int s = s0 + ty + r * 8;
    tile[ty + r * 8][tx] =
        kvlin[((size_t)(b * S_ + s)) * 2048 + 1024 + kv * HD_ + d0 + tx];
  }
  __syncthreads();
#pragma unroll
  for (int r = 0; r < 4; ++r) {
    const int d = d0 + ty + r * 8;
    vt[((size_t)bk * HD_ + d) * S_ + s0 + tx] = tile[tx][ty + r * 8];
  }
}

// ---------------- causal GQA flash attention (unchanged) ----------------------
__global__ __launch_bounds__(256, 2)
void attn_kernel(const u16* __restrict__ Q, const u16* __restrict__ K,
                 const u16* __restrict__ V, u16* __restrict__ O) {
  __shared__ u16 sK[2][64 * HD_];
  __shared__ u16 sV[2][HD_ * 64];
  const int tid = threadIdx.x;
  const int w = tid >> 6, l = tid & 63;
  const int hi = l >> 5, q32 = l & 31;
  const int kv = blockIdx.y, b = blockIdx.z;
  const int h = kv * 4 + w;
  const u16* Kp = K + ((size_t)(b * KVH_ + kv) * S_) * HD_;
  const u16* Vp = V + ((size_t)(b * KVH_ + kv) * HD_) * S_;

  int koff[4], voff[4];
#pragma unroll
  for (int i = 0; i < 4; ++i) {
    const int kr = w * 16 + i * 4 + (l >> 4);
    koff[i] = kr * HD_ + (((l & 15) ^ (kr & 7))) * 8;
    const int vr = w * 32 + i * 8 + (l >> 3);
    voff[i] = vr * S_ + (((l & 7) ^ (vr & 7))) * 8;
  }
  int cx[8];
#pragma unroll
  for (int c = 0; c < 8; ++c) cx[c] = ((c * 2 + hi) ^ (l & 7)) * 8;

  auto STAGE = [&](int bufi, int ti) {
    const u16* kg = Kp + (size_t)ti * (64 * HD_);
    const u16* vg = Vp + (size_t)ti * 64;
#pragma unroll
    for (int i = 0; i < 4; ++i) {
      gl_lds16(kg + koff[i], &sK[bufi][(w * 16 + i * 4) * HD_]);
      gl_lds16(vg + voff[i], &sV[bufi][(w * 32 + i * 8) * 64]);
    }
  };

  int cur = 0;
  for (int seg = 0; seg < 2; ++seg) {
    const int qt = seg ? (63 - blockIdx.x) : blockIdx.x;
    const int qg = qt * 32 + q32;
    const u16* Qp = Q + ((size_t)(b * H_ + h) * S_ + qt * 32) * HD_;

    bf16x8 qf[8];
#pragma unroll
    for (int ds = 0; ds < 8; ++ds)
      qf[ds] = *(const bf16x8*)(Qp + (size_t)q32 * HD_ + ds * 16 + hi * 8);
    asm volatile("s_waitcnt vmcnt(0)" ::: "memory");

    f32x16 out[4];
#pragma unroll
    for (int d = 0; d < 4; ++d)
#pragma unroll
      for (int r = 0; r < 16; ++r) out[d][r] = 0.f;
    float mrun = -1e30f, lrun = 0.f;

    const int nt = (qt >> 1) + 1;
    STAGE(cur, 0);

    for (int t = 0; t < nt; ++t) {
      if (t + 1 < nt) {
        STAGE(cur ^ 1, t + 1);
        asm volatile("s_waitcnt vmcnt(8)" ::: "memory");
      } else {
        asm volatile("s_waitcnt vmcnt(0)" ::: "memory");
      }
      __builtin_amdgcn_s_barrier();
      asm volatile("" ::: "memory");

      f32x16 sc0, sc1;
#pragma unroll
      for (int r = 0; r < 16; ++r) { sc0[r] = 0.f; sc1[r] = 0.f; }
      __builtin_amdgcn_s_setprio(1);
#pragma unroll
      for (int ds = 0; ds < 8; ++ds) {
        bf16x8 kf0 = *(const bf16x8*)&sK[cur][q32 * HD_ + cx[ds]];
        bf16x8 kf1 = *(const bf16x8*)&sK[cur][(32 + q32) * HD_ + cx[ds]];
        sc0 = MFMA32(kf0, qf[ds], sc0);
        sc1 = MFMA32(kf1, qf[ds], sc1);
      }
      __builtin_amdgcn_s_setprio(0);

      const bool diag = (t == nt - 1);
      float p0[16], p1[16];
#pragma unroll
      for (int r = 0; r < 16; ++r) {
        const int krow = (r & 3) + 8 * (r >> 2) + 4 * hi;
        float v0 = sc0[r], v1 = sc1[r];
        if (diag) {
          if (t * 64 + krow > qg) v0 = -1e9f;
          if (t * 64 + 32 + krow > qg) v1 = -1e9f;
        }
        p0[r] = v0; p1[r] = v1;
      }
      float rm = -1e30f;
#pragma unroll
      for (int r = 0; r < 16; ++r) rm = fmaxf(rm, fmaxf(p0[r], p1[r]));
      rm = fmaxf(rm, __shfl_xor(rm, 32, 64));
      if (!__all(rm <= mrun + 8.0f)) {
        const float mnew = fmaxf(mrun, rm);
        const float alpha = exp2v(mrun - mnew);
        mrun = mnew;
        lrun *= alpha;
#pragma unroll
        for (int d = 0; d < 4; ++d) out[d] *= alpha;
      }
      float sum = 0.f;
#pragma unroll
      for (int r = 0; r < 16; ++r) {
        p0[r] = exp2v(p0[r] - mrun);
        p1[r] = exp2v(p1[r] - mrun);
        sum += p0[r] + p1[r];
      }
      sum += __shfl_xor(sum, 32, 64);
      lrun += sum;
      uint32_t pk0[8], pk1[8];
#pragma unroll
      for (int g = 0; g < 4; ++g) {
        pk0[2 * g]     = cvtpk(p0[4 * g], p0[4 * g + 1]);
        pk0[2 * g + 1] = cvtpk(p0[4 * g + 2], p0[4 * g + 3]);
        pk1[2 * g]     = cvtpk(p1[4 * g], p1[4 * g + 1]);
        pk1[2 * g + 1] = cvtpk(p1[4 * g + 2], p1[4 * g + 3]);
      }
      PLSWAP(pk0[0], pk0[2]); PLSWAP(pk0[1], pk0[3]);
      PLSWAP(pk0[4], pk0[6]); PLSWAP(pk0[5], pk0[7]);
      PLSWAP(pk1[0], pk1[2]); PLSWAP(pk1[1], pk1[3]);
      PLSWAP(pk1[4], pk1[6]); PLSWAP(pk1[5], pk1[7]);
      bf16x8 pa[4];
      pa[0] = __builtin_bit_cast(bf16x8, (u32x4){pk0[0], pk0[1], pk0[2], pk0[3]});
      pa[1] = __builtin_bit_cast(bf16x8, (u32x4){pk0[4], pk0[5], pk0[6], pk0[7]});
      pa[2] = __builtin_bit_cast(bf16x8, (u32x4){pk1[0], pk1[1], pk1[2], pk1[3]});
      pa[3] = __builtin_bit_cast(bf16x8, (u32x4){pk1[4], pk1[5], pk1[6], pk1[7]});
      __builtin_amdgcn_s_setprio(1);
#pragma unroll
      for (int d = 0; d < 4; ++d) {
        const int vbase = (d * 32 + q32) * 64;
#pragma unroll
        for (int kk = 0; kk < 4; ++kk) {
          bf16x8 vf = *(const bf16x8*)&sV[cur][vbase + cx[kk]];
          out[d] = MFMA32(vf, pa[kk], out[d]);
        }
      }
      __builtin_amdgcn_s_setprio(0);
      asm volatile("" ::: "memory");
      __builtin_amdgcn_s_barrier();
      cur ^= 1;
    }

    const float inv = 1.0f / lrun;
    u16* myS = ((u16*)sK) + w * 4096;
#pragma unroll
    for (int d = 0; d < 4; ++d)
#pragma unroll
      for (int rq = 0; rq < 4; ++rq) {
        u32x2 pw;
        pw[0] = cvtpk(out[d][rq * 4 + 0] * inv, out[d][rq * 4 + 1] * inv);
        pw[1] = cvtpk(out[d][rq * 4 + 2] * inv, out[d][rq * 4 + 3] * inv);
        const int gin = (d * 8 + rq * 2 + hi) ^ (q32 & 15);
        *(u32x2*)&myS[q32 * 128 + gin * 4] = pw;
      }
    asm volatile("s_waitcnt lgkmcnt(0)" ::: "memory");
    __builtin_amdgcn_sched_barrier(0);
    const int rr = l >> 4;
    const int cc = l & 15;
#pragma unroll
    for (int p = 0; p < 8; ++p) {
      const int q = p * 4 + rr;
      const int ga = (2 * cc) ^ (q & 15);
      const int gb = (2 * cc + 1) ^ (q & 15);
      u32x2 va = *(const u32x2*)&myS[q * 128 + ga * 4];
      u32x2 vb = *(const u32x2*)&myS[q * 128 + gb * 4];
      u32x4 val = {va[0], va[1], vb[0], vb[1]};
      *(u32x4*)&O[((size_t)(b * S_ + qt * 32 + q)) * (H_ * HD_) + h * HD_ + cc * 8] = val;
    }
    if (seg == 0) {
      asm volatile("" ::: "memory");
      __builtin_amdgcn_s_barrier();
    }
  }
}

// ---------------- launch ----------------
extern "C" void kernel_launch(void* const* d_in, const int* in_sizes, int n_in,
                              void* d_out, int out_size, void* d_ws, size_t ws_size,
                              hipStream_t stream) {
  const float* x     = (const float*)d_in[0];
  const float* freqs = (const float*)d_in[2];
  const float* wq    = (const float*)d_in[4];
  const float* wk    = (const float*)d_in[5];
  const float* wv    = (const float*)d_in[6];
  const float* wo    = (const float*)d_in[7];

  char* ws = (char*)d_ws;
  u16* xb    = (u16*)(ws + 0);          // bf16 x, later bf16 wo
  u16* wqb   = (u16*)(ws + 33554432);   // bf16 wq, later attn output
  u16* wkb   = (u16*)(ws + 67108864);   // bf16 wk, later rope'd K
  u16* wvb   = (u16*)(ws + 75497472);   // bf16 wv, later V^T
  u16* qrope = (u16*)(ws + 83886080);   // rope'd Q [B][H][S][128]
  u16* kvlin = (u16*)(ws + 117440512);  // fused [4096][2048] bf16
  u16* kr   = wkb;
  u16* vt   = wvb;
  u16* aout = wqb;
  u16* wob  = xb;

  const float qscale = 0.08838834764831845f * 1.4426950408889634f;

  cast4_kernel<<<20480, 256, 0, stream>>>(x, wq, wk, wv, xb, wqb, wkb, wvb);
  gemm256_bt<2><<<256, 512, 0, stream>>>(xb, wqb, qrope, 4096, 4096, 4096,
                                         freqs, qscale);
  gemm_bt<false><<<dim3(16, 32), 256, 0, stream>>>(xb, wkb, kvlin, 4096, 2048, 4096);
  rope_kernel<8, 2048, 0><<<8192, 256, 0, stream>>>(kvlin, freqs, kr, 1.0f);
  vtrans_kernel<<<dim3(64, 4, 16), dim3(32, 8), 0, stream>>>(kvlin, vt);
  attn_kernel<<<dim3(32, 8, 2), 256, 0, stream>>>(qrope, kr, vt, aout);
  cast_kernel<<<8192, 256, 0, stream>>>(wo, wob, 2097152);
  gemm256_bt<1><<<256, 512, 0, stream>>>(aout, wob, d_out, 4096, 4096, 4096,
                                         nullptr, 0.f);
}

// Round 20
// 488.065 us; speedup vs baseline: 1.0629x; 1.0629x over previous
//
#include <hip/hip_runtime.h>
#include <cstdint>
#include <cstddef>

#define B_   2
#define S_   2048
#define D_   4096
#define H_   32
#define KVH_ 8
#define HD_  128

typedef unsigned short u16;
typedef short     bf16x8 __attribute__((ext_vector_type(8)));
typedef float     f32x4  __attribute__((ext_vector_type(4)));
typedef float     f32x16 __attribute__((ext_vector_type(16)));
typedef u16       u16x8  __attribute__((ext_vector_type(8)));
typedef uint32_t  u32x2  __attribute__((ext_vector_type(2)));
typedef uint32_t  u32x4  __attribute__((ext_vector_type(4)));

__device__ __forceinline__ u16 f2bf(float f) {
  union { float f; uint32_t u; } v; v.f = f;
  uint32_t u = v.u;
  return (u16)((u + 0x7fffu + ((u >> 16) & 1u)) >> 16);
}
__device__ __forceinline__ float bf2f(u16 h) {
  union { uint32_t u; float f; } v; v.u = ((uint32_t)h) << 16;
  return v.f;
}
__device__ __forceinline__ uint32_t cvtpk(float lo, float hi_) {
  uint32_t r; asm("v_cvt_pk_bf16_f32 %0, %1, %2" : "=v"(r) : "v"(lo), "v"(hi_)); return r;
}
__device__ __forceinline__ float exp2v(float x) {
  float r; asm("v_exp_f32 %0, %1" : "=v"(r) : "v"(x)); return r;
}

__device__ __forceinline__ void gl_lds16(const void* g, void* l) {
  __builtin_amdgcn_global_load_lds(
      (const __attribute__((address_space(1))) void*)g,
      (__attribute__((address_space(3))) void*)l, 16, 0, 0);
}

#define MFMA(a, b, c)  __builtin_amdgcn_mfma_f32_16x16x32_bf16((a), (b), (c), 0, 0, 0)
#define MFMA32(a, b, c) __builtin_amdgcn_mfma_f32_32x32x16_bf16((a), (b), (c), 0, 0, 0)
#define PLSWAP(x, y) asm volatile("v_permlane32_swap_b32 %0, %1" : "+v"(x), "+v"(y))

// ---------------- merged cast f32 -> bf16 (x, wq, wk, wv in one launch) -------
__global__ void cast4_kernel(const float* __restrict__ x, const float* __restrict__ wq,
                             const float* __restrict__ wk, const float* __restrict__ wv,
                             u16* __restrict__ xb, u16* __restrict__ wqb,
                             u16* __restrict__ wkb, u16* __restrict__ wvb) {
  int i = blockIdx.x * 256 + threadIdx.x;   // u16x8 group index, total 5242880
  const float* src; u16* dst; int off;
  if (i < 2097152)      { src = x;  dst = xb;  off = i; }
  else if (i < 4194304) { src = wq; dst = wqb; off = i - 2097152; }
  else if (i < 4718592) { src = wk; dst = wkb; off = i - 4194304; }
  else                  { src = wv; dst = wvb; off = i - 4718592; }
  const float4* p = (const float4*)src + (size_t)off * 2;
  float4 a = p[0], b = p[1];
  u16x8 r;
  r[0] = f2bf(a.x); r[1] = f2bf(a.y); r[2] = f2bf(a.z); r[3] = f2bf(a.w);
  r[4] = f2bf(b.x); r[5] = f2bf(b.y); r[6] = f2bf(b.z); r[7] = f2bf(b.w);
  *((u16x8*)dst + off) = r;
}

__global__ void cast_kernel(const float* __restrict__ in, u16* __restrict__ out, int n8) {
  int i = blockIdx.x * blockDim.x + threadIdx.x;
  if (i >= n8) return;
  const float4* p = (const float4*)in + (size_t)i * 2;
  float4 a = p[0], b = p[1];
  u16x8 r;
  r[0] = f2bf(a.x); r[1] = f2bf(a.y); r[2] = f2bf(a.z); r[3] = f2bf(a.w);
  r[4] = f2bf(b.x); r[5] = f2bf(b.y); r[6] = f2bf(b.z); r[7] = f2bf(b.w);
  *((u16x8*)out + i) = r;
}

// ---------------- GEMM-NT 128^2 (known-good; used for fused K/V proj) ---------
template <bool OUT_F32>
__global__ __launch_bounds__(256, 2)
void gemm_bt(const u16* __restrict__ A, const u16* __restrict__ Bw,
             void* __restrict__ C, int M, int N, int K) {
  __shared__ u16 lA[128 * 32];
  __shared__ u16 lB[128 * 32];
  const int tid = threadIdx.x;
  const int w = tid >> 6, l = tid & 63;
  const int lc = l & 15, lg = l >> 4;
  const int bn = blockIdx.x, bm = blockIdx.y;
  const int wr = w >> 1, wc = w & 1;
  const u16* Ab = A + (size_t)(bm * 128) * K;
  const u16* Bb = Bw + (size_t)(bn * 128) * K;
  const int srow = l >> 2;
  const int scol = (l & 3) * 8;

  f32x4 acc[4][4];
#pragma unroll
  for (int i = 0; i < 4; ++i)
#pragma unroll
    for (int j = 0; j < 4; ++j) acc[i][j] = (f32x4){0.f, 0.f, 0.f, 0.f};

  const int nk = K >> 5;
  for (int kt = 0; kt < nk; ++kt) {
    const int k0 = kt * 32;
    __syncthreads();
#pragma unroll
    for (int i = 0; i < 2; ++i) {
      const int rowA = (w * 2 + i) * 16;
      gl_lds16(Ab + (size_t)(rowA + srow) * K + k0 + scol, &lA[rowA * 32]);
      gl_lds16(Bb + (size_t)(rowA + srow) * K + k0 + scol, &lB[rowA * 32]);
    }
    __syncthreads();
    bf16x8 af[4], bfr[4];
#pragma unroll
    for (int mi = 0; mi < 4; ++mi)
      af[mi] = *(const bf16x8*)&lA[(wr * 64 + mi * 16 + lc) * 32 + lg * 8];
#pragma unroll
    for (int ni = 0; ni < 4; ++ni)
      bfr[ni] = *(const bf16x8*)&lB[(wc * 64 + ni * 16 + lc) * 32 + lg * 8];
#pragma unroll
    for (int mi = 0; mi < 4; ++mi)
#pragma unroll
      for (int ni = 0; ni < 4; ++ni)
        acc[mi][ni] = MFMA(af[mi], bfr[ni], acc[mi][ni]);
  }

#pragma unroll
  for (int mi = 0; mi < 4; ++mi)
#pragma unroll
    for (int ni = 0; ni < 4; ++ni)
#pragma unroll
      for (int r = 0; r < 4; ++r) {
        const int row = bm * 128 + wr * 64 + mi * 16 + lg * 4 + r;
        const int col = bn * 128 + wc * 64 + ni * 16 + lc;
        if constexpr (OUT_F32)
          ((float*)C)[(size_t)row * N + col] = acc[mi][ni][r];
        else
          ((u16*)C)[(size_t)row * N + col] = f2bf(acc[mi][ni][r]);
      }
}

// ---------------- GEMM-NT 256^2, BK=64, Gray-code, SINGLE vmcnt/tile ----------
// r15-proven schedule (best measured: 133 us, MfmaUtil 45.5%, 0 bank
// conflicts). At t.P0, tile t's 4 halves are the 8 oldest outstanding loads
// with only t+1:A0,B0 behind -> VMW(4) drains all of tile t. Ordering per
// phase: vmcnt -> barrier -> reads. Reads: P0 A0+B0(12), P1 B1(4), P2 A1(8),
// P3 none = 24/wave/tile. MODE: 0 bf16 C, 1 f32 C, 2 fused Q-RoPE.
template <int MODE>
__global__ __launch_bounds__(512, 2)
void gemm256_bt(const u16* __restrict__ A, const u16* __restrict__ Bw,
                void* __restrict__ C, int M, int N, int K,
                const float* __restrict__ fr, float qscale) {
  __shared__ u16 sA[2 * 256 * 64];
  __shared__ u16 sB[2 * 256 * 64];
  const int tid = threadIdx.x;
  const int w = tid >> 6, l = tid & 63;
  const int lc = l & 15, lg = l >> 4;
  const int wm = w >> 2, wn = w & 3;          // 2 x 4 wave grid
  const int nbn = N >> 8;
  const int nwg = (M >> 8) * nbn;
  const int cpx = nwg >> 3;
  const int lin = blockIdx.x;
  const int swz = (lin & 7) * cpx + (lin >> 3);
  const int bm = swz / nbn, bn = swz % nbn;
  const u16* Ab = A + (size_t)(bm * 256) * K;
  const u16* Bb = Bw + (size_t)(bn * 256) * K;
  const int lr = l >> 3;
  const int scc = ((l & 7) ^ lr) * 8;
  int cxg[2];
#pragma unroll
  for (int kk = 0; kk < 2; ++kk) cxg[kk] = ((kk * 4 + lg) ^ (lc & 7)) * 8;

  f32x4 acc[8][4];
#pragma unroll
  for (int i = 0; i < 8; ++i)
#pragma unroll
    for (int j = 0; j < 4; ++j) acc[i][j] = (f32x4){0.f, 0.f, 0.f, 0.f};

  auto STAGEA = [&](int buf, int t1, int h) {
    const int k0 = t1 * 64;
#pragma unroll
    for (int j = 0; j < 2; ++j) {
      const int r0 = h * 128 + w * 16 + j * 8;
      gl_lds16(Ab + (size_t)(r0 + lr) * K + k0 + scc, &sA[buf * 16384 + r0 * 64]);
    }
  };
  auto STAGEB = [&](int buf, int t1, int h) {
    const int k0 = t1 * 64;
#pragma unroll
    for (int j = 0; j < 2; ++j) {
      const int r0 = h * 128 + w * 16 + j * 8;
      gl_lds16(Bb + (size_t)(r0 + lr) * K + k0 + scc, &sB[buf * 16384 + r0 * 64]);
    }
  };

  bf16x8 a0r[4][2], a1r[4][2], b0r[2][2], b1r[2][2];
  auto LDA0 = [&](int cb) {
#pragma unroll
    for (int mi = 0; mi < 4; ++mi)
#pragma unroll
      for (int kk = 0; kk < 2; ++kk)
        a0r[mi][kk] = *(const bf16x8*)
            &sA[cb + (wm * 64 + mi * 16 + lc) * 64 + cxg[kk]];
  };
  auto LDA1 = [&](int cb) {
#pragma unroll
    for (int mi = 0; mi < 4; ++mi)
#pragma unroll
      for (int kk = 0; kk < 2; ++kk)
        a1r[mi][kk] = *(const bf16x8*)
            &sA[cb + (128 + wm * 64 + mi * 16 + lc) * 64 + cxg[kk]];
  };
  auto LDB0 = [&](int cb) {
#pragma unroll
    for (int ni = 0; ni < 2; ++ni)
#pragma unroll
      for (int kk = 0; kk < 2; ++kk)
        b0r[ni][kk] = *(const bf16x8*)
            &sB[cb + (wn * 32 + ni * 16 + lc) * 64 + cxg[kk]];
  };
  auto LDB1 = [&](int cb) {
#pragma unroll
    for (int ni = 0; ni < 2; ++ni)
#pragma unroll
      for (int kk = 0; kk < 2; ++kk)
        b1r[ni][kk] = *(const bf16x8*)
            &sB[cb + (128 + wn * 32 + ni * 16 + lc) * 64 + cxg[kk]];
  };

#define VMW(N_) asm volatile("s_waitcnt vmcnt(" #N_ ")" ::: "memory")
#define BARR do { __builtin_amdgcn_s_barrier(); asm volatile("" ::: "memory"); } while (0)
#define LGKM do { asm volatile("s_waitcnt lgkmcnt(0)" ::: "memory"); \
                  __builtin_amdgcn_sched_barrier(0); } while (0)
#define MMQ(AF, HA, HB, BF) do { __builtin_amdgcn_s_setprio(1); \
  _Pragma("unroll") for (int kk = 0; kk < 2; ++kk) \
  _Pragma("unroll") for (int mi = 0; mi < 4; ++mi) \
  _Pragma("unroll") for (int ni = 0; ni < 2; ++ni) \
    acc[(HA) * 4 + mi][(HB) * 2 + ni] = \
        MFMA(AF[mi][kk], BF[ni][kk], acc[(HA) * 4 + mi][(HB) * 2 + ni]); \
  __builtin_amdgcn_s_setprio(0); } while (0)

  const int nk = K >> 6;
  // prologue: queue order [t0:A0, t0:B0, t0:B1, t0:A1, t1:A0, t1:B0] (12 loads)
  STAGEA(0, 0, 0); STAGEB(0, 0, 0);
  STAGEB(0, 0, 1); STAGEA(0, 0, 1);
  STAGEA(1, 1, 0); STAGEB(1, 1, 0);

  for (int t = 0; t < nk; ++t) {
    const int cur = t & 1;
    const int cb = cur * 16384;
    const int nb = cur ^ 1;
    const bool n1 = (t + 1 < nk), n2 = (t + 2 < nk);

    // ---- P0: quadrant (0,0); reads A0+B0. SINGLE wait drains all of tile t --
    if (n1) VMW(4); else VMW(0);
    BARR;
    LDA0(cb); LDB0(cb);
    if (n1) { STAGEB(nb, t + 1, 1); STAGEA(nb, t + 1, 1); }
    LGKM;
    MMQ(a0r, 0, 0, b0r);

    // ---- P1: quadrant (0,1); reads B1 (already landed; no wait) ----
    BARR;
    LDB1(cb);
    LGKM;
    MMQ(a0r, 0, 1, b1r);

    // ---- P2: quadrant (1,1); reads A1 (already landed; no wait) ----
    BARR;
    LDA1(cb);
    if (n2) STAGEA(cur, t + 2, 0);
    LGKM;
    MMQ(a1r, 1, 1, b1r);

    // ---- P3: quadrant (1,0); no reads ----
    if (n2) STAGEB(cur, t + 2, 0);
    MMQ(a1r, 1, 0, b0r);
  }
#undef VMW
#undef BARR
#undef LGKM
#undef MMQ

  // ---- epilogue ----
#pragma unroll
  for (int ha = 0; ha < 2; ++ha)
#pragma unroll
    for (int mi = 0; mi < 4; ++mi)
#pragma unroll
      for (int hb = 0; hb < 2; ++hb)
#pragma unroll
        for (int ni = 0; ni < 2; ++ni)
#pragma unroll
          for (int r = 0; r < 4; ++r) {
            const int row = bm * 256 + ha * 128 + wm * 64 + mi * 16 + lg * 4 + r;
            const int col = bn * 256 + hb * 128 + wn * 32 + ni * 16 + lc;
            const float v = acc[ha * 4 + mi][hb * 2 + ni][r];
            if constexpr (MODE == 1) {
              ((float*)C)[(size_t)row * N + col] = v;
            } else if constexpr (MODE == 0) {
              ((u16*)C)[(size_t)row * N + col] = f2bf(v);
            } else {
              const float pv = __shfl_xor(v, 1, 64);
              const int b = row >> 11, s = row & (S_ - 1);
              const int h = col >> 7, d = col & 127;
              const float2 cs = ((const float2*)fr)[s * 64 + (d >> 1)];
              const float o = ((lc & 1) == 0) ? (v * cs.x - pv * cs.y)
                                              : (v * cs.x + pv * cs.y);
              ((u16*)C)[(((size_t)(b * H_ + h) * S_ + s)) * HD_ + d] =
                  f2bf(o * qscale);
            }
          }
}

// ---------------- RoPE (row stride / col offset parametrized) ----------------
template <int NH, int STRIDE, int OFF>
__global__ void rope_kernel(const u16* __restrict__ lin, const float* __restrict__ fr,
                            u16* __restrict__ out, float scale) {
  int idx = blockIdx.x * 256 + threadIdx.x;
  const int total = B_ * S_ * NH * 64;
  if (idx >= total) return;
  const int i = idx & 63;
  const int h = (idx >> 6) % NH;
  const int t = idx / (64 * NH);
  const int s = t & (S_ - 1);
  const int b = t >> 11;
  const size_t src = (size_t)t * STRIDE + OFF + h * HD_ + 2 * i;
  const float x0 = bf2f(lin[src]);
  const float x1 = bf2f(lin[src + 1]);
  const float2 cs = ((const float2*)fr)[s * 64 + i];
  const float o0 = (x0 * cs.x - x1 * cs.y) * scale;
  const float o1 = (x1 * cs.x + x0 * cs.y) * scale;
  const size_t dst = ((size_t)((b * NH + h) * S_ + s)) * HD_ + 2 * i;
  out[dst] = f2bf(o0);
  out[dst + 1] = f2bf(o1);
}

// ---------------- V transpose (reads fused KV buffer, V at col offset 1024) ---
__global__ void vtrans_kernel(const u16* __restrict__ kvlin, u16* __restrict__ vt) {
  __shared__ u16 tile[32][33];
  const int tx = threadIdx.x, ty = threadIdx.y;  // (32, 8)
  const int s0 = blockIdx.x * 32;
  const int d0 = blockIdx.y * 32;
  const int bk = blockIdx.z;
  const int b = bk >> 3, kv = bk & 7;
#pragma unroll
  for (int r = 0; r < 4; ++r) {
    const int s = s0 + ty + r * 8;
    tile[ty + r * 8][tx] =
        kvlin[((size_t)(b * S_ + s)) * 2048 + 1024 + kv * HD_ + d0 + tx];
  }
  __syncthreads();
#pragma unroll
  for (int r = 0; r < 4; ++r) {
    const int d = d0 + ty + r * 8;
    vt[((size_t)bk * HD_ + d) * S_ + s0 + tx] = tile[tx][ty + r * 8];
  }
}

// ---------------- causal GQA flash attention (unchanged) ----------------------
__global__ __launch_bounds__(256, 2)
void attn_kernel(const u16* __restrict__ Q, const u16* __restrict__ K,
                 const u16* __restrict__ V, u16* __restrict__ O) {
  __shared__ u16 sK[2][64 * HD_];
  __shared__ u16 sV[2][HD_ * 64];
  const int tid = threadIdx.x;
  const int w = tid >> 6, l = tid & 63;
  const int hi = l >> 5, q32 = l & 31;
  const int kv = blockIdx.y, b = blockIdx.z;
  const int h = kv * 4 + w;
  const u16* Kp = K + ((size_t)(b * KVH_ + kv) * S_) * HD_;
  const u16* Vp = V + ((size_t)(b * KVH_ + kv) * HD_) * S_;

  int koff[4], voff[4];
#pragma unroll
  for (int i = 0; i < 4; ++i) {
    const int kr = w * 16 + i * 4 + (l >> 4);
    koff[i] = kr * HD_ + (((l & 15) ^ (kr & 7))) * 8;
    const int vr = w * 32 + i * 8 + (l >> 3);
    voff[i] = vr * S_ + (((l & 7) ^ (vr & 7))) * 8;
  }
  int cx[8];
#pragma unroll
  for (int c = 0; c < 8; ++c) cx[c] = ((c * 2 + hi) ^ (l & 7)) * 8;

  auto STAGE = [&](int bufi, int ti) {
    const u16* kg = Kp + (size_t)ti * (64 * HD_);
    const u16* vg = Vp + (size_t)ti * 64;
#pragma unroll
    for (int i = 0; i < 4; ++i) {
      gl_lds16(kg + koff[i], &sK[bufi][(w * 16 + i * 4) * HD_]);
      gl_lds16(vg + voff[i], &sV[bufi][(w * 32 + i * 8) * 64]);
    }
  };

  int cur = 0;
  for (int seg = 0; seg < 2; ++seg) {
    const int qt = seg ? (63 - blockIdx.x) : blockIdx.x;
    const int qg = qt * 32 + q32;
    const u16* Qp = Q + ((size_t)(b * H_ + h) * S_ + qt * 32) * HD_;

    bf16x8 qf[8];
#pragma unroll
    for (int ds = 0; ds < 8; ++ds)
      qf[ds] = *(const bf16x8*)(Qp + (size_t)q32 * HD_ + ds * 16 + hi * 8);
    asm volatile("s_waitcnt vmcnt(0)" ::: "memory");

    f32x16 out[4];
#pragma unroll
    for (int d = 0; d < 4; ++d)
#pragma unroll
      for (int r = 0; r < 16; ++r) out[d][r] = 0.f;
    float mrun = -1e30f, lrun = 0.f;

    const int nt = (qt >> 1) + 1;
    STAGE(cur, 0);

    for (int t = 0; t < nt; ++t) {
      if (t + 1 < nt) {
        STAGE(cur ^ 1, t + 1);
        asm volatile("s_waitcnt vmcnt(8)" ::: "memory");
      } else {
        asm volatile("s_waitcnt vmcnt(0)" ::: "memory");
      }
      __builtin_amdgcn_s_barrier();
      asm volatile("" ::: "memory");

      f32x16 sc0, sc1;
#pragma unroll
      for (int r = 0; r < 16; ++r) { sc0[r] = 0.f; sc1[r] = 0.f; }
      __builtin_amdgcn_s_setprio(1);
#pragma unroll
      for (int ds = 0; ds < 8; ++ds) {
        bf16x8 kf0 = *(const bf16x8*)&sK[cur][q32 * HD_ + cx[ds]];
        bf16x8 kf1 = *(const bf16x8*)&sK[cur][(32 + q32) * HD_ + cx[ds]];
        sc0 = MFMA32(kf0, qf[ds], sc0);
        sc1 = MFMA32(kf1, qf[ds], sc1);
      }
      __builtin_amdgcn_s_setprio(0);

      const bool diag = (t == nt - 1);
      float p0[16], p1[16];
#pragma unroll
      for (int r = 0; r < 16; ++r) {
        const int krow = (r & 3) + 8 * (r >> 2) + 4 * hi;
        float v0 = sc0[r], v1 = sc1[r];
        if (diag) {
          if (t * 64 + krow > qg) v0 = -1e9f;
          if (t * 64 + 32 + krow > qg) v1 = -1e9f;
        }
        p0[r] = v0; p1[r] = v1;
      }
      float rm = -1e30f;
#pragma unroll
      for (int r = 0; r < 16; ++r) rm = fmaxf(rm, fmaxf(p0[r], p1[r]));
      rm = fmaxf(rm, __shfl_xor(rm, 32, 64));
      if (!__all(rm <= mrun + 8.0f)) {
        const float mnew = fmaxf(mrun, rm);
        const float alpha = exp2v(mrun - mnew);
        mrun = mnew;
        lrun *= alpha;
#pragma unroll
        for (int d = 0; d < 4; ++d) out[d] *= alpha;
      }
      float sum = 0.f;
#pragma unroll
      for (int r = 0; r < 16; ++r) {
        p0[r] = exp2v(p0[r] - mrun);
        p1[r] = exp2v(p1[r] - mrun);
        sum += p0[r] + p1[r];
      }
      sum += __shfl_xor(sum, 32, 64);
      lrun += sum;
      uint32_t pk0[8], pk1[8];
#pragma unroll
      for (int g = 0; g < 4; ++g) {
        pk0[2 * g]     = cvtpk(p0[4 * g], p0[4 * g + 1]);
        pk0[2 * g + 1] = cvtpk(p0[4 * g + 2], p0[4 * g + 3]);
        pk1[2 * g]     = cvtpk(p1[4 * g], p1[4 * g + 1]);
        pk1[2 * g + 1] = cvtpk(p1[4 * g + 2], p1[4 * g + 3]);
      }
      PLSWAP(pk0[0], pk0[2]); PLSWAP(pk0[1], pk0[3]);
      PLSWAP(pk0[4], pk0[6]); PLSWAP(pk0[5], pk0[7]);
      PLSWAP(pk1[0], pk1[2]); PLSWAP(pk1[1], pk1[3]);
      PLSWAP(pk1[4], pk1[6]); PLSWAP(pk1[5], pk1[7]);
      bf16x8 pa[4];
      pa[0] = __builtin_bit_cast(bf16x8, (u32x4){pk0[0], pk0[1], pk0[2], pk0[3]});
      pa[1] = __builtin_bit_cast(bf16x8, (u32x4){pk0[4], pk0[5], pk0[6], pk0[7]});
      pa[2] = __builtin_bit_cast(bf16x8, (u32x4){pk1[0], pk1[1], pk1[2], pk1[3]});
      pa[3] = __builtin_bit_cast(bf16x8, (u32x4){pk1[4], pk1[5], pk1[6], pk1[7]});
      __builtin_amdgcn_s_setprio(1);
#pragma unroll
      for (int d = 0; d < 4; ++d) {
        const int vbase = (d * 32 + q32) * 64;
#pragma unroll
        for (int kk = 0; kk < 4; ++kk) {
          bf16x8 vf = *(const bf16x8*)&sV[cur][vbase + cx[kk]];
          out[d] = MFMA32(vf, pa[kk], out[d]);
        }
      }
      __builtin_amdgcn_s_setprio(0);
      asm volatile("" ::: "memory");
      __builtin_amdgcn_s_barrier();
      cur ^= 1;
    }

    const float inv = 1.0f / lrun;
    u16* myS = ((u16*)sK) + w * 4096;
#pragma unroll
    for (int d = 0; d < 4; ++d)
#pragma unroll
      for (int rq = 0; rq < 4; ++rq) {
        u32x2 pw;
        pw[0] = cvtpk(out[d][rq * 4 + 0] * inv, out[d][rq * 4 + 1] * inv);
        pw[1] = cvtpk(out[d][rq * 4 + 2] * inv, out[d][rq * 4 + 3] * inv);
        const int gin = (d * 8 + rq * 2 + hi) ^ (q32 & 15);
        *(u32x2*)&myS[q32 * 128 + gin * 4] = pw;
      }
    asm volatile("s_waitcnt lgkmcnt(0)" ::: "memory");
    __builtin_amdgcn_sched_barrier(0);
    const int rr = l >> 4;
    const int cc = l & 15;
#pragma unroll
    for (int p = 0; p < 8; ++p) {
      const int q = p * 4 + rr;
      const int ga = (2 * cc) ^ (q & 15);
      const int gb = (2 * cc + 1) ^ (q & 15);
      u32x2 va = *(const u32x2*)&myS[q * 128 + ga * 4];
      u32x2 vb = *(const u32x2*)&myS[q * 128 + gb * 4];
      u32x4 val = {va[0], va[1], vb[0], vb[1]};
      *(u32x4*)&O[((size_t)(b * S_ + qt * 32 + q)) * (H_ * HD_) + h * HD_ + cc * 8] = val;
    }
    if (seg == 0) {
      asm volatile("" ::: "memory");
      __builtin_amdgcn_s_barrier();
    }
  }
}

// ---------------- launch ----------------
extern "C" void kernel_launch(void* const* d_in, const int* in_sizes, int n_in,
                              void* d_out, int out_size, void* d_ws, size_t ws_size,
                              hipStream_t stream) {
  const float* x     = (const float*)d_in[0];
  const float* freqs = (const float*)d_in[2];
  const float* wq    = (const float*)d_in[4];
  const float* wk    = (const float*)d_in[5];
  const float* wv    = (const float*)d_in[6];
  const float* wo    = (const float*)d_in[7];

  char* ws = (char*)d_ws;
  u16* xb    = (u16*)(ws + 0);          // bf16 x, later bf16 wo
  u16* wqb   = (u16*)(ws + 33554432);   // bf16 wq, later attn output
  u16* wkb   = (u16*)(ws + 67108864);   // bf16 wk, later rope'd K
  u16* wvb   = (u16*)(ws + 75497472);   // bf16 wv, later V^T
  u16* qrope = (u16*)(ws + 83886080);   // rope'd Q [B][H][S][128]
  u16* kvlin = (u16*)(ws + 117440512);  // fused [4096][2048] bf16
  u16* kr   = wkb;
  u16* vt   = wvb;
  u16* aout = wqb;
  u16* wob  = xb;

  const float qscale = 0.08838834764831845f * 1.4426950408889634f;

  cast4_kernel<<<20480, 256, 0, stream>>>(x, wq, wk, wv, xb, wqb, wkb, wvb);
  gemm256_bt<2><<<256, 512, 0, stream>>>(xb, wqb, qrope, 4096, 4096, 4096,
                                         freqs, qscale);
  gemm_bt<false><<<dim3(16, 32), 256, 0, stream>>>(xb, wkb, kvlin, 4096, 2048, 4096);
  rope_kernel<8, 2048, 0><<<8192, 256, 0, stream>>>(kvlin, freqs, kr, 1.0f);
  vtrans_kernel<<<dim3(64, 4, 16), dim3(32, 8), 0, stream>>>(kvlin, vt);
  attn_kernel<<<dim3(32, 8, 2), 256, 0, stream>>>(qrope, kr, vt, aout);
  cast_kernel<<<8192, 256, 0, stream>>>(wo, wob, 2097152);
  gemm256_bt<1><<<256, 512, 0, stream>>>(aout, wob, d_out, 4096, 4096, 4096,
                                         nullptr, 0.f);
}

// Round 21
// 483.888 us; speedup vs baseline: 1.0721x; 1.0086x over previous
//
#include <hip/hip_runtime.h>
#include <cstdint>
#include <cstddef>

#define B_   2
#define S_   2048
#define D_   4096
#define H_   32
#define KVH_ 8
#define HD_  128

typedef unsigned short u16;
typedef short     bf16x8 __attribute__((ext_vector_type(8)));
typedef float     f32x4  __attribute__((ext_vector_type(4)));
typedef float     f32x16 __attribute__((ext_vector_type(16)));
typedef u16       u16x8  __attribute__((ext_vector_type(8)));
typedef uint32_t  u32x2  __attribute__((ext_vector_type(2)));
typedef uint32_t  u32x4  __attribute__((ext_vector_type(4)));

__device__ __forceinline__ u16 f2bf(float f) {
  union { float f; uint32_t u; } v; v.f = f;
  uint32_t u = v.u;
  return (u16)((u + 0x7fffu + ((u >> 16) & 1u)) >> 16);
}
__device__ __forceinline__ float bf2f(u16 h) {
  union { uint32_t u; float f; } v; v.u = ((uint32_t)h) << 16;
  return v.f;
}
__device__ __forceinline__ uint32_t cvtpk(float lo, float hi_) {
  uint32_t r; asm("v_cvt_pk_bf16_f32 %0, %1, %2" : "=v"(r) : "v"(lo), "v"(hi_)); return r;
}
__device__ __forceinline__ float exp2v(float x) {
  float r; asm("v_exp_f32 %0, %1" : "=v"(r) : "v"(x)); return r;
}

__device__ __forceinline__ void gl_lds16(const void* g, void* l) {
  __builtin_amdgcn_global_load_lds(
      (const __attribute__((address_space(1))) void*)g,
      (__attribute__((address_space(3))) void*)l, 16, 0, 0);
}

#define MFMA(a, b, c)  __builtin_amdgcn_mfma_f32_16x16x32_bf16((a), (b), (c), 0, 0, 0)
#define MFMA32(a, b, c) __builtin_amdgcn_mfma_f32_32x32x16_bf16((a), (b), (c), 0, 0, 0)
#define PLSWAP(x, y) asm volatile("v_permlane32_swap_b32 %0, %1" : "+v"(x), "+v"(y))

// ---------------- merged cast f32 -> bf16 (x, wq, wk, wv in one launch) -------
__global__ void cast4_kernel(const float* __restrict__ x, const float* __restrict__ wq,
                             const float* __restrict__ wk, const float* __restrict__ wv,
                             u16* __restrict__ xb, u16* __restrict__ wqb,
                             u16* __restrict__ wkb, u16* __restrict__ wvb) {
  int i = blockIdx.x * 256 + threadIdx.x;   // u16x8 group index, total 5242880
  const float* src; u16* dst; int off;
  if (i < 2097152)      { src = x;  dst = xb;  off = i; }
  else if (i < 4194304) { src = wq; dst = wqb; off = i - 2097152; }
  else if (i < 4718592) { src = wk; dst = wkb; off = i - 4194304; }
  else                  { src = wv; dst = wvb; off = i - 4718592; }
  const float4* p = (const float4*)src + (size_t)off * 2;
  float4 a = p[0], b = p[1];
  u16x8 r;
  r[0] = f2bf(a.x); r[1] = f2bf(a.y); r[2] = f2bf(a.z); r[3] = f2bf(a.w);
  r[4] = f2bf(b.x); r[5] = f2bf(b.y); r[6] = f2bf(b.z); r[7] = f2bf(b.w);
  *((u16x8*)dst + off) = r;
}

// ---------------- GEMM-NT 128^2 (known-good; used for fused K/V proj) ---------
template <bool OUT_F32>
__global__ __launch_bounds__(256, 2)
void gemm_bt(const u16* __restrict__ A, const u16* __restrict__ Bw,
             void* __restrict__ C, int M, int N, int K) {
  __shared__ u16 lA[128 * 32];
  __shared__ u16 lB[128 * 32];
  const int tid = threadIdx.x;
  const int w = tid >> 6, l = tid & 63;
  const int lc = l & 15, lg = l >> 4;
  const int bn = blockIdx.x, bm = blockIdx.y;
  const int wr = w >> 1, wc = w & 1;
  const u16* Ab = A + (size_t)(bm * 128) * K;
  const u16* Bb = Bw + (size_t)(bn * 128) * K;
  const int srow = l >> 2;
  const int scol = (l & 3) * 8;

  f32x4 acc[4][4];
#pragma unroll
  for (int i = 0; i < 4; ++i)
#pragma unroll
    for (int j = 0; j < 4; ++j) acc[i][j] = (f32x4){0.f, 0.f, 0.f, 0.f};

  const int nk = K >> 5;
  for (int kt = 0; kt < nk; ++kt) {
    const int k0 = kt * 32;
    __syncthreads();
#pragma unroll
    for (int i = 0; i < 2; ++i) {
      const int rowA = (w * 2 + i) * 16;
      gl_lds16(Ab + (size_t)(rowA + srow) * K + k0 + scol, &lA[rowA * 32]);
      gl_lds16(Bb + (size_t)(rowA + srow) * K + k0 + scol, &lB[rowA * 32]);
    }
    __syncthreads();
    bf16x8 af[4], bfr[4];
#pragma unroll
    for (int mi = 0; mi < 4; ++mi)
      af[mi] = *(const bf16x8*)&lA[(wr * 64 + mi * 16 + lc) * 32 + lg * 8];
#pragma unroll
    for (int ni = 0; ni < 4; ++ni)
      bfr[ni] = *(const bf16x8*)&lB[(wc * 64 + ni * 16 + lc) * 32 + lg * 8];
#pragma unroll
    for (int mi = 0; mi < 4; ++mi)
#pragma unroll
      for (int ni = 0; ni < 4; ++ni)
        acc[mi][ni] = MFMA(af[mi], bfr[ni], acc[mi][ni]);
  }

#pragma unroll
  for (int mi = 0; mi < 4; ++mi)
#pragma unroll
    for (int ni = 0; ni < 4; ++ni)
#pragma unroll
      for (int r = 0; r < 4; ++r) {
        const int row = bm * 128 + wr * 64 + mi * 16 + lg * 4 + r;
        const int col = bn * 128 + wc * 64 + ni * 16 + lc;
        if constexpr (OUT_F32)
          ((float*)C)[(size_t)row * N + col] = acc[mi][ni][r];
        else
          ((u16*)C)[(size_t)row * N + col] = f2bf(acc[mi][ni][r]);
      }
}

// ---------------- GEMM-NT 256^2, BK=64, Gray-code, SINGLE vmcnt/tile ----------
// r15-proven schedule (best measured: 133 us, MfmaUtil 45.5%, 0 bank
// conflicts). At t.P0, tile t's 4 halves are the 8 oldest outstanding loads
// with only t+1:A0,B0 behind -> VMW(4) drains all of tile t. Ordering per
// phase: vmcnt -> barrier -> reads. Reads: P0 A0+B0(12), P1 B1(4), P2 A1(8),
// P3 none = 24/wave/tile. MODE: 0 bf16 C, 1 f32 C, 2 fused Q-RoPE.
template <int MODE>
__global__ __launch_bounds__(512, 2)
void gemm256_bt(const u16* __restrict__ A, const u16* __restrict__ Bw,
                void* __restrict__ C, int M, int N, int K,
                const float* __restrict__ fr, float qscale) {
  __shared__ u16 sA[2 * 256 * 64];
  __shared__ u16 sB[2 * 256 * 64];
  const int tid = threadIdx.x;
  const int w = tid >> 6, l = tid & 63;
  const int lc = l & 15, lg = l >> 4;
  const int wm = w >> 2, wn = w & 3;          // 2 x 4 wave grid
  const int nbn = N >> 8;
  const int nwg = (M >> 8) * nbn;
  const int cpx = nwg >> 3;
  const int lin = blockIdx.x;
  const int swz = (lin & 7) * cpx + (lin >> 3);
  const int bm = swz / nbn, bn = swz % nbn;
  const u16* Ab = A + (size_t)(bm * 256) * K;
  const u16* Bb = Bw + (size_t)(bn * 256) * K;
  const int lr = l >> 3;
  const int scc = ((l & 7) ^ lr) * 8;
  int cxg[2];
#pragma unroll
  for (int kk = 0; kk < 2; ++kk) cxg[kk] = ((kk * 4 + lg) ^ (lc & 7)) * 8;

  f32x4 acc[8][4];
#pragma unroll
  for (int i = 0; i < 8; ++i)
#pragma unroll
    for (int j = 0; j < 4; ++j) acc[i][j] = (f32x4){0.f, 0.f, 0.f, 0.f};

  auto STAGEA = [&](int buf, int t1, int h) {
    const int k0 = t1 * 64;
#pragma unroll
    for (int j = 0; j < 2; ++j) {
      const int r0 = h * 128 + w * 16 + j * 8;
      gl_lds16(Ab + (size_t)(r0 + lr) * K + k0 + scc, &sA[buf * 16384 + r0 * 64]);
    }
  };
  auto STAGEB = [&](int buf, int t1, int h) {
    const int k0 = t1 * 64;
#pragma unroll
    for (int j = 0; j < 2; ++j) {
      const int r0 = h * 128 + w * 16 + j * 8;
      gl_lds16(Bb + (size_t)(r0 + lr) * K + k0 + scc, &sB[buf * 16384 + r0 * 64]);
    }
  };

  bf16x8 a0r[4][2], a1r[4][2], b0r[2][2], b1r[2][2];
  auto LDA0 = [&](int cb) {
#pragma unroll
    for (int mi = 0; mi < 4; ++mi)
#pragma unroll
      for (int kk = 0; kk < 2; ++kk)
        a0r[mi][kk] = *(const bf16x8*)
            &sA[cb + (wm * 64 + mi * 16 + lc) * 64 + cxg[kk]];
  };
  auto LDA1 = [&](int cb) {
#pragma unroll
    for (int mi = 0; mi < 4; ++mi)
#pragma unroll
      for (int kk = 0; kk < 2; ++kk)
        a1r[mi][kk] = *(const bf16x8*)
            &sA[cb + (128 + wm * 64 + mi * 16 + lc) * 64 + cxg[kk]];
  };
  auto LDB0 = [&](int cb) {
#pragma unroll
    for (int ni = 0; ni < 2; ++ni)
#pragma unroll
      for (int kk = 0; kk < 2; ++kk)
        b0r[ni][kk] = *(const bf16x8*)
            &sB[cb + (wn * 32 + ni * 16 + lc) * 64 + cxg[kk]];
  };
  auto LDB1 = [&](int cb) {
#pragma unroll
    for (int ni = 0; ni < 2; ++ni)
#pragma unroll
      for (int kk = 0; kk < 2; ++kk)
        b1r[ni][kk] = *(const bf16x8*)
            &sB[cb + (128 + wn * 32 + ni * 16 + lc) * 64 + cxg[kk]];
  };

#define VMW(N_) asm volatile("s_waitcnt vmcnt(" #N_ ")" ::: "memory")
#define BARR do { __builtin_amdgcn_s_barrier(); asm volatile("" ::: "memory"); } while (0)
#define LGKM do { asm volatile("s_waitcnt lgkmcnt(0)" ::: "memory"); \
                  __builtin_amdgcn_sched_barrier(0); } while (0)
#define MMQ(AF, HA, HB, BF) do { __builtin_amdgcn_s_setprio(1); \
  _Pragma("unroll") for (int kk = 0; kk < 2; ++kk) \
  _Pragma("unroll") for (int mi = 0; mi < 4; ++mi) \
  _Pragma("unroll") for (int ni = 0; ni < 2; ++ni) \
    acc[(HA) * 4 + mi][(HB) * 2 + ni] = \
        MFMA(AF[mi][kk], BF[ni][kk], acc[(HA) * 4 + mi][(HB) * 2 + ni]); \
  __builtin_amdgcn_s_setprio(0); } while (0)

  const int nk = K >> 6;
  // prologue: queue order [t0:A0, t0:B0, t0:B1, t0:A1, t1:A0, t1:B0] (12 loads)
  STAGEA(0, 0, 0); STAGEB(0, 0, 0);
  STAGEB(0, 0, 1); STAGEA(0, 0, 1);
  STAGEA(1, 1, 0); STAGEB(1, 1, 0);

  for (int t = 0; t < nk; ++t) {
    const int cur = t & 1;
    const int cb = cur * 16384;
    const int nb = cur ^ 1;
    const bool n1 = (t + 1 < nk), n2 = (t + 2 < nk);

    // ---- P0: quadrant (0,0); reads A0+B0. SINGLE wait drains all of tile t --
    if (n1) VMW(4); else VMW(0);
    BARR;
    LDA0(cb); LDB0(cb);
    if (n1) { STAGEB(nb, t + 1, 1); STAGEA(nb, t + 1, 1); }
    LGKM;
    MMQ(a0r, 0, 0, b0r);

    // ---- P1: quadrant (0,1); reads B1 (already landed; no wait) ----
    BARR;
    LDB1(cb);
    LGKM;
    MMQ(a0r, 0, 1, b1r);

    // ---- P2: quadrant (1,1); reads A1 (already landed; no wait) ----
    BARR;
    LDA1(cb);
    if (n2) STAGEA(cur, t + 2, 0);
    LGKM;
    MMQ(a1r, 1, 1, b1r);

    // ---- P3: quadrant (1,0); no reads ----
    if (n2) STAGEB(cur, t + 2, 0);
    MMQ(a1r, 1, 0, b0r);
  }
#undef VMW
#undef BARR
#undef LGKM
#undef MMQ

  // ---- epilogue ----
#pragma unroll
  for (int ha = 0; ha < 2; ++ha)
#pragma unroll
    for (int mi = 0; mi < 4; ++mi)
#pragma unroll
      for (int hb = 0; hb < 2; ++hb)
#pragma unroll
        for (int ni = 0; ni < 2; ++ni)
#pragma unroll
          for (int r = 0; r < 4; ++r) {
            const int row = bm * 256 + ha * 128 + wm * 64 + mi * 16 + lg * 4 + r;
            const int col = bn * 256 + hb * 128 + wn * 32 + ni * 16 + lc;
            const float v = acc[ha * 4 + mi][hb * 2 + ni][r];
            if constexpr (MODE == 1) {
              ((float*)C)[(size_t)row * N + col] = v;
            } else if constexpr (MODE == 0) {
              ((u16*)C)[(size_t)row * N + col] = f2bf(v);
            } else {
              const float pv = __shfl_xor(v, 1, 64);
              const int b = row >> 11, s = row & (S_ - 1);
              const int h = col >> 7, d = col & 127;
              const float2 cs = ((const float2*)fr)[s * 64 + (d >> 1)];
              const float o = ((lc & 1) == 0) ? (v * cs.x - pv * cs.y)
                                              : (v * cs.x + pv * cs.y);
              ((u16*)C)[(((size_t)(b * H_ + h) * S_ + s)) * HD_ + d] =
                  f2bf(o * qscale);
            }
          }
}

// ---------------- merged post-KV kernel: K-RoPE + V-transpose + wo cast -------
// All three are independent and legal right after gemm_kv (xb dead, kvlin
// ready). Blocks [0,8192): rope-K; [8192,12288): vtrans; [12288,20480): wo cast.
__global__ void ropekv_kernel(const u16* __restrict__ kvlin,
                              const float* __restrict__ fr,
                              u16* __restrict__ kr, u16* __restrict__ vt,
                              const float* __restrict__ wo, u16* __restrict__ wob) {
  const int tid = threadIdx.x;
  if (blockIdx.x < 8192) {
    // ---- K rope: [t][2048] cols 0-1023 -> [b][kv][s][128]
    const int idx = blockIdx.x * 256 + tid;
    const int i = idx & 63;
    const int h = (idx >> 6) & 7;
    const int t = idx >> 9;
    const int s = t & (S_ - 1);
    const int b = t >> 11;
    const size_t src = (size_t)t * 2048 + h * HD_ + 2 * i;
    const float x0 = bf2f(kvlin[src]);
    const float x1 = bf2f(kvlin[src + 1]);
    const float2 cs = ((const float2*)fr)[s * 64 + i];
    const size_t dst = ((size_t)((b * KVH_ + h) * S_ + s)) * HD_ + 2 * i;
    kr[dst]     = f2bf(x0 * cs.x - x1 * cs.y);
    kr[dst + 1] = f2bf(x1 * cs.x + x0 * cs.y);
  } else if (blockIdx.x < 12288) {
    // ---- V transpose: kvlin cols 1024-2047 -> vt [b][kv][d][s]
    __shared__ u16 tile[32][33];
    const int bid = blockIdx.x - 8192;
    const int tx = tid & 31, ty = tid >> 5;   // (32, 8)
    const int s0 = (bid & 63) * 32;
    const int d0 = ((bid >> 6) & 3) * 32;
    const int bk = bid >> 8;
    const int b = bk >> 3, kv = bk & 7;
#pragma unroll
    for (int r = 0; r < 4; ++r) {
      const int s = s0 + ty + r * 8;
      tile[ty + r * 8][tx] =
          kvlin[((size_t)(b * S_ + s)) * 2048 + 1024 + kv * HD_ + d0 + tx];
    }
    __syncthreads();
#pragma unroll
    for (int r = 0; r < 4; ++r) {
      const int d = d0 + ty + r * 8;
      vt[((size_t)bk * HD_ + d) * S_ + s0 + tx] = tile[tx][ty + r * 8];
    }
  } else {
    // ---- wo cast f32 -> bf16 (xb region is dead after gemm_kv)
    const int off = (blockIdx.x - 12288) * 256 + tid;   // < 2097152
    const float4* p = (const float4*)wo + (size_t)off * 2;
    float4 a = p[0], b = p[1];
    u16x8 r;
    r[0] = f2bf(a.x); r[1] = f2bf(a.y); r[2] = f2bf(a.z); r[3] = f2bf(a.w);
    r[4] = f2bf(b.x); r[5] = f2bf(b.y); r[6] = f2bf(b.z); r[7] = f2bf(b.w);
    *((u16x8*)wob + off) = r;
  }
}

// ---------------- causal GQA flash attention (unchanged) ----------------------
__global__ __launch_bounds__(256, 2)
void attn_kernel(const u16* __restrict__ Q, const u16* __restrict__ K,
                 const u16* __restrict__ V, u16* __restrict__ O) {
  __shared__ u16 sK[2][64 * HD_];
  __shared__ u16 sV[2][HD_ * 64];
  const int tid = threadIdx.x;
  const int w = tid >> 6, l = tid & 63;
  const int hi = l >> 5, q32 = l & 31;
  const int kv = blockIdx.y, b = blockIdx.z;
  const int h = kv * 4 + w;
  const u16* Kp = K + ((size_t)(b * KVH_ + kv) * S_) * HD_;
  const u16* Vp = V + ((size_t)(b * KVH_ + kv) * HD_) * S_;

  int koff[4], voff[4];
#pragma unroll
  for (int i = 0; i < 4; ++i) {
    const int kr = w * 16 + i * 4 + (l >> 4);
    koff[i] = kr * HD_ + (((l & 15) ^ (kr & 7))) * 8;
    const int vr = w * 32 + i * 8 + (l >> 3);
    voff[i] = vr * S_ + (((l & 7) ^ (vr & 7))) * 8;
  }
  int cx[8];
#pragma unroll
  for (int c = 0; c < 8; ++c) cx[c] = ((c * 2 + hi) ^ (l & 7)) * 8;

  auto STAGE = [&](int bufi, int ti) {
    const u16* kg = Kp + (size_t)ti * (64 * HD_);
    const u16* vg = Vp + (size_t)ti * 64;
#pragma unroll
    for (int i = 0; i < 4; ++i) {
      gl_lds16(kg + koff[i], &sK[bufi][(w * 16 + i * 4) * HD_]);
      gl_lds16(vg + voff[i], &sV[bufi][(w * 32 + i * 8) * 64]);
    }
  };

  int cur = 0;
  for (int seg = 0; seg < 2; ++seg) {
    const int qt = seg ? (63 - blockIdx.x) : blockIdx.x;
    const int qg = qt * 32 + q32;
    const u16* Qp = Q + ((size_t)(b * H_ + h) * S_ + qt * 32) * HD_;

    bf16x8 qf[8];
#pragma unroll
    for (int ds = 0; ds < 8; ++ds)
      qf[ds] = *(const bf16x8*)(Qp + (size_t)q32 * HD_ + ds * 16 + hi * 8);
    asm volatile("s_waitcnt vmcnt(0)" ::: "memory");

    f32x16 out[4];
#pragma unroll
    for (int d = 0; d < 4; ++d)
#pragma unroll
      for (int r = 0; r < 16; ++r) out[d][r] = 0.f;
    float mrun = -1e30f, lrun = 0.f;

    const int nt = (qt >> 1) + 1;
    STAGE(cur, 0);

    for (int t = 0; t < nt; ++t) {
      if (t + 1 < nt) {
        STAGE(cur ^ 1, t + 1);
        asm volatile("s_waitcnt vmcnt(8)" ::: "memory");
      } else {
        asm volatile("s_waitcnt vmcnt(0)" ::: "memory");
      }
      __builtin_amdgcn_s_barrier();
      asm volatile("" ::: "memory");

      f32x16 sc0, sc1;
#pragma unroll
      for (int r = 0; r < 16; ++r) { sc0[r] = 0.f; sc1[r] = 0.f; }
      __builtin_amdgcn_s_setprio(1);
#pragma unroll
      for (int ds = 0; ds < 8; ++ds) {
        bf16x8 kf0 = *(const bf16x8*)&sK[cur][q32 * HD_ + cx[ds]];
        bf16x8 kf1 = *(const bf16x8*)&sK[cur][(32 + q32) * HD_ + cx[ds]];
        sc0 = MFMA32(kf0, qf[ds], sc0);
        sc1 = MFMA32(kf1, qf[ds], sc1);
      }
      __builtin_amdgcn_s_setprio(0);

      const bool diag = (t == nt - 1);
      float p0[16], p1[16];
#pragma unroll
      for (int r = 0; r < 16; ++r) {
        const int krow = (r & 3) + 8 * (r >> 2) + 4 * hi;
        float v0 = sc0[r], v1 = sc1[r];
        if (diag) {
          if (t * 64 + krow > qg) v0 = -1e9f;
          if (t * 64 + 32 + krow > qg) v1 = -1e9f;
        }
        p0[r] = v0; p1[r] = v1;
      }
      float rm = -1e30f;
#pragma unroll
      for (int r = 0; r < 16; ++r) rm = fmaxf(rm, fmaxf(p0[r], p1[r]));
      rm = fmaxf(rm, __shfl_xor(rm, 32, 64));
      if (!__all(rm <= mrun + 8.0f)) {
        const float mnew = fmaxf(mrun, rm);
        const float alpha = exp2v(mrun - mnew);
        mrun = mnew;
        lrun *= alpha;
#pragma unroll
        for (int d = 0; d < 4; ++d) out[d] *= alpha;
      }
      float sum = 0.f;
#pragma unroll
      for (int r = 0; r < 16; ++r) {
        p0[r] = exp2v(p0[r] - mrun);
        p1[r] = exp2v(p1[r] - mrun);
        sum += p0[r] + p1[r];
      }
      sum += __shfl_xor(sum, 32, 64);
      lrun += sum;
      uint32_t pk0[8], pk1[8];
#pragma unroll
      for (int g = 0; g < 4; ++g) {
        pk0[2 * g]     = cvtpk(p0[4 * g], p0[4 * g + 1]);
        pk0[2 * g + 1] = cvtpk(p0[4 * g + 2], p0[4 * g + 3]);
        pk1[2 * g]     = cvtpk(p1[4 * g], p1[4 * g + 1]);
        pk1[2 * g + 1] = cvtpk(p1[4 * g + 2], p1[4 * g + 3]);
      }
      PLSWAP(pk0[0], pk0[2]); PLSWAP(pk0[1], pk0[3]);
      PLSWAP(pk0[4], pk0[6]); PLSWAP(pk0[5], pk0[7]);
      PLSWAP(pk1[0], pk1[2]); PLSWAP(pk1[1], pk1[3]);
      PLSWAP(pk1[4], pk1[6]); PLSWAP(pk1[5], pk1[7]);
      bf16x8 pa[4];
      pa[0] = __builtin_bit_cast(bf16x8, (u32x4){pk0[0], pk0[1], pk0[2], pk0[3]});
      pa[1] = __builtin_bit_cast(bf16x8, (u32x4){pk0[4], pk0[5], pk0[6], pk0[7]});
      pa[2] = __builtin_bit_cast(bf16x8, (u32x4){pk1[0], pk1[1], pk1[2], pk1[3]});
      pa[3] = __builtin_bit_cast(bf16x8, (u32x4){pk1[4], pk1[5], pk1[6], pk1[7]});
      __builtin_amdgcn_s_setprio(1);
#pragma unroll
      for (int d = 0; d < 4; ++d) {
        const int vbase = (d * 32 + q32) * 64;
#pragma unroll
        for (int kk = 0; kk < 4; ++kk) {
          bf16x8 vf = *(const bf16x8*)&sV[cur][vbase + cx[kk]];
          out[d] = MFMA32(vf, pa[kk], out[d]);
        }
      }
      __builtin_amdgcn_s_setprio(0);
      asm volatile("" ::: "memory");
      __builtin_amdgcn_s_barrier();
      cur ^= 1;
    }

    const float inv = 1.0f / lrun;
    u16* myS = ((u16*)sK) + w * 4096;
#pragma unroll
    for (int d = 0; d < 4; ++d)
#pragma unroll
      for (int rq = 0; rq < 4; ++rq) {
        u32x2 pw;
        pw[0] = cvtpk(out[d][rq * 4 + 0] * inv, out[d][rq * 4 + 1] * inv);
        pw[1] = cvtpk(out[d][rq * 4 + 2] * inv, out[d][rq * 4 + 3] * inv);
        const int gin = (d * 8 + rq * 2 + hi) ^ (q32 & 15);
        *(u32x2*)&myS[q32 * 128 + gin * 4] = pw;
      }
    asm volatile("s_waitcnt lgkmcnt(0)" ::: "memory");
    __builtin_amdgcn_sched_barrier(0);
    const int rr = l >> 4;
    const int cc = l & 15;
#pragma unroll
    for (int p = 0; p < 8; ++p) {
      const int q = p * 4 + rr;
      const int ga = (2 * cc) ^ (q & 15);
      const int gb = (2 * cc + 1) ^ (q & 15);
      u32x2 va = *(const u32x2*)&myS[q * 128 + ga * 4];
      u32x2 vb = *(const u32x2*)&myS[q * 128 + gb * 4];
      u32x4 val = {va[0], va[1], vb[0], vb[1]};
      *(u32x4*)&O[((size_t)(b * S_ + qt * 32 + q)) * (H_ * HD_) + h * HD_ + cc * 8] = val;
    }
    if (seg == 0) {
      asm volatile("" ::: "memory");
      __builtin_amdgcn_s_barrier();
    }
  }
}

// ---------------- launch ----------------
extern "C" void kernel_launch(void* const* d_in, const int* in_sizes, int n_in,
                              void* d_out, int out_size, void* d_ws, size_t ws_size,
                              hipStream_t stream) {
  const float* x     = (const float*)d_in[0];
  const float* freqs = (const float*)d_in[2];
  const float* wq    = (const float*)d_in[4];
  const float* wk    = (const float*)d_in[5];
  const float* wv    = (const float*)d_in[6];
  const float* wo    = (const float*)d_in[7];

  char* ws = (char*)d_ws;
  u16* xb    = (u16*)(ws + 0);          // bf16 x, later bf16 wo
  u16* wqb   = (u16*)(ws + 33554432);   // bf16 wq, later attn output
  u16* wkb   = (u16*)(ws + 67108864);   // bf16 wk, later rope'd K
  u16* wvb   = (u16*)(ws + 75497472);   // bf16 wv, later V^T
  u16* qrope = (u16*)(ws + 83886080);   // rope'd Q [B][H][S][128]
  u16* kvlin = (u16*)(ws + 117440512);  // fused [4096][2048] bf16
  u16* kr   = wkb;
  u16* vt   = wvb;
  u16* aout = wqb;
  u16* wob  = xb;

  const float qscale = 0.08838834764831845f * 1.4426950408889634f;

  cast4_kernel<<<20480, 256, 0, stream>>>(x, wq, wk, wv, xb, wqb, wkb, wvb);
  gemm256_bt<2><<<256, 512, 0, stream>>>(xb, wqb, qrope, 4096, 4096, 4096,
                                         freqs, qscale);
  gemm_bt<false><<<dim3(16, 32), 256, 0, stream>>>(xb, wkb, kvlin, 4096, 2048, 4096);
  ropekv_kernel<<<20480, 256, 0, stream>>>(kvlin, freqs, kr, vt, wo, wob);
  attn_kernel<<<dim3(32, 8, 2), 256, 0, stream>>>(qrope, kr, vt, aout);
  gemm256_bt<1><<<256, 512, 0, stream>>>(aout, wob, d_out, 4096, 4096, 4096,
                                         nullptr, 0.f);
}